// Round 5
// baseline (722.146 us; speedup 1.0000x reference)
//
#include <hip/hip_runtime.h>
#include <hip/hip_bf16.h>

// Problem constants (from reference)
#define N_NODES 50000
#define N_EDGES 640000
#define F_IN 64
#define EDGE_DIM 16
#define HID 128
#define N_LAYERS 3
#define NUM_GRAPHS 64
#define BN_EPS 1e-5f

typedef __attribute__((ext_vector_type(8))) short short8;    // 8 bf16 (4 VGPRs)
typedef __attribute__((ext_vector_type(4))) float f32x4;     // MFMA acc
typedef __attribute__((ext_vector_type(2))) __fp16 half2v;   // packed f16 pair
typedef __attribute__((ext_vector_type(8))) __fp16 half8;    // 8 f16 (4 VGPRs) MFMA frag

// bf16 <-> f32 helpers (manual, RNE on pack)
__device__ __forceinline__ float bfl(unsigned int u) {
    unsigned int v = u << 16; float f; __builtin_memcpy(&f, &v, 4); return f;
}
__device__ __forceinline__ float bfh(unsigned int u) {
    unsigned int v = u & 0xffff0000u; float f; __builtin_memcpy(&f, &v, 4); return f;
}
__device__ __forceinline__ unsigned int f2bf(float f) {
    unsigned int v; __builtin_memcpy(&v, &f, 4);
    v += 0x7fffu + ((v >> 16) & 1u);
    return v >> 16;
}
__device__ __forceinline__ unsigned int pack2(float lo, float hi) {
    return f2bf(lo) | (f2bf(hi) << 16);
}
__device__ __forceinline__ unsigned int pkh(float a, float b) {
    half2v h = __builtin_amdgcn_cvt_pkrtz(a, b);
    unsigned int u; __builtin_memcpy(&u, &h, 4); return u;
}

// ---------------------------------------------------------------------------
// CSR build
// ---------------------------------------------------------------------------
__global__ void k_hist(const int* __restrict__ dst, int* __restrict__ deg) {
    int e = blockIdx.x * 256 + threadIdx.x;   // grid exact: 2500*256 = 640000
    atomicAdd(&deg[dst[e]], 1);
}

__global__ void k_blockred(const int* __restrict__ deg, int* __restrict__ bsums) {
    __shared__ int s[256];
    int i = blockIdx.x * 256 + threadIdx.x;
    int v = (i < N_NODES) ? deg[i] : 0;
    s[threadIdx.x] = v;
    __syncthreads();
    for (int off = 128; off > 0; off >>= 1) {
        if (threadIdx.x < off) s[threadIdx.x] += s[threadIdx.x + off];
        __syncthreads();
    }
    if (threadIdx.x == 0) bsums[blockIdx.x] = s[0];
}

// parallel exclusive scan of block sums (nb <= 256, one block)
__global__ void k_scan_bsums(int* __restrict__ bsums, int nb) {
    __shared__ int s[256];
    const int tid = threadIdx.x;
    const int v = (tid < nb) ? bsums[tid] : 0;
    s[tid] = v;
    __syncthreads();
    for (int off = 1; off < 256; off <<= 1) {
        int t = 0;
        if (tid >= off) t = s[tid - off];
        __syncthreads();
        s[tid] += t;
        __syncthreads();
    }
    if (tid < nb) bsums[tid] = s[tid] - v;
}

__global__ void k_scan_blocks(int* __restrict__ deg_rowptr, const int* __restrict__ bsums,
                              int* __restrict__ cursor) {
    __shared__ int s[256];
    int tid = threadIdx.x;
    int i = blockIdx.x * 256 + tid;
    int v = (i < N_NODES) ? deg_rowptr[i] : 0;
    s[tid] = v;
    __syncthreads();
    for (int off = 1; off < 256; off <<= 1) {
        int t = 0;
        if (tid >= off) t = s[tid - off];
        __syncthreads();
        s[tid] += t;
        __syncthreads();
    }
    int excl = s[tid] - v + bsums[blockIdx.x];
    if (i < N_NODES) {
        deg_rowptr[i] = excl;
        cursor[i] = excl;
    }
    if (i == N_NODES - 1) deg_rowptr[N_NODES] = N_EDGES;
}

// ---------------------------------------------------------------------------
// Fused fill + edge materialization: reads esrc/edst/eattr COALESCED in
// original edge order, one atomicAdd for the CSR slot, scatters src_s (4B)
// and f16-packed eattr (32B) to the slot. Replaces the old k_fill+k_gather
// pair (which did random 64B eattr reads through an elist indirection).
// ---------------------------------------------------------------------------
__global__ __launch_bounds__(256) void k_fill(const int* __restrict__ esrc,
                                              const int* __restrict__ edst,
                                              const float* __restrict__ eattr,
                                              int* __restrict__ cursor,
                                              int* __restrict__ src_s,
                                              uint4* __restrict__ eattr_h) {
    const int e = blockIdx.x * 256 + threadIdx.x;   // exact: 2500*256 = 640000
    const int s = esrc[e];
    const int d = edst[e];
    const float* ep = eattr + (size_t)e * EDGE_DIM;
    const float4 a0 = *(const float4*)ep;
    const float4 a1 = *(const float4*)(ep + 4);
    const float4 a2 = *(const float4*)(ep + 8);
    const float4 a3 = *(const float4*)(ep + 12);
    const int p = atomicAdd(&cursor[d], 1);
    src_s[p] = s;
    eattr_h[p * 2] = make_uint4(pkh(a0.x, a0.y), pkh(a0.z, a0.w),
                                pkh(a1.x, a1.y), pkh(a1.z, a1.w));
    eattr_h[p * 2 + 1] = make_uint4(pkh(a2.x, a2.y), pkh(a2.z, a2.w),
                                    pkh(a3.x, a3.y), pkh(a3.z, a3.w));
}

// ---------------------------------------------------------------------------
// Merged weight packing: [0,12288) = W1/W2 MFMA B-frags, [12288,13312) =
// enc_W B-frags, [13312,16384) = edge-weight f16 MFMA B-frags (wekf).
// wekf layout per layer: 8 n-frags x 64 lanes x 8 halves. B column c of frag
// nt maps to feature 8*c+nt (so a lane's 8 output features are contiguous).
// k = 8*(lane>>4)+j; k<16 -> W[k][f]; k==16 -> bias[f] (A supplies 1.0 there).
// ---------------------------------------------------------------------------
__global__ void k_pack(const float* __restrict__ W1, const float* __restrict__ W2,
                       const float* __restrict__ encW, const float* __restrict__ eW,
                       const float* __restrict__ eb2,
                       unsigned short* __restrict__ wp, unsigned short* __restrict__ wpe,
                       unsigned short* __restrict__ wekf) {
    const int t = blockIdx.x * 256 + threadIdx.x;   // 64*256 = 16384 exact
    if (t < 12288) {
        const int mat = t >> 11;
        const int r = t & 2047;
        const int kstep = r >> 9;
        const int ntile = (r >> 6) & 7;
        const int lane = r & 63;
        const float* W = (mat < 3) ? (W1 + mat * 16384) : (W2 + (mat - 3) * 16384);
        const int kbase = kstep * 32 + ((lane >> 4) << 3);
        const int n = ntile * 16 + (lane & 15);
        unsigned int o[4];
#pragma unroll
        for (int jj = 0; jj < 4; ++jj)
            o[jj] = pack2(W[(kbase + 2 * jj) * HID + n], W[(kbase + 2 * jj + 1) * HID + n]);
        *(uint4*)(wp + (size_t)mat * 16384 + (((kstep << 3) + ntile) * 64 + lane) * 8) =
            make_uint4(o[0], o[1], o[2], o[3]);
    } else if (t < 13312) {
        const int r = t - 12288;
        const int kstep = r >> 9;
        const int ntile = (r >> 6) & 7;
        const int lane = r & 63;
        const int kbase = kstep * 32 + ((lane >> 4) << 3);
        const int n = ntile * 16 + (lane & 15);
        unsigned int o[4];
#pragma unroll
        for (int jj = 0; jj < 4; ++jj)
            o[jj] = pack2(encW[(kbase + 2 * jj) * HID + n], encW[(kbase + 2 * jj + 1) * HID + n]);
        *(uint4*)(wpe + (((kstep << 3) + ntile) * 64 + lane) * 8) =
            make_uint4(o[0], o[1], o[2], o[3]);
    } else {
        const int r = t - 13312;                    // 0..3071, 4 halves each
        const int l = r >> 10;
        const int rr = r & 1023;
        const int nt = rr >> 7;
        const int lane = (rr >> 1) & 63;
        const int hf = rr & 1;
        const int qq = lane >> 4;
        const int f = ((lane & 15) << 3) + nt;      // permuted column -> feature
        float v[4];
#pragma unroll
        for (int j = 0; j < 4; ++j) {
            const int k = (qq << 3) + (hf << 2) + j;
            v[j] = (k < 16) ? eW[(l * EDGE_DIM + k) * HID + f]
                            : ((k == 16) ? eb2[l * HID + f] : 0.f);
        }
        *(uint2*)(wekf + (((l * 8 + nt) * 64 + lane) * 8) + (hf << 2)) =
            make_uint2(pkh(v[0], v[1]), pkh(v[2], v[3]));
    }
}

// ---------------------------------------------------------------------------
// Encoder via MFMA: hb = bf16(x @ enc_W + enc_b), reads fp32 x directly.
// ---------------------------------------------------------------------------
__global__ __launch_bounds__(256, 3) void k_encm(const float* __restrict__ x,
                                                 const unsigned short* __restrict__ wpe,
                                                 const float* __restrict__ b,
                                                 unsigned short* __restrict__ hb) {
    const int tid = threadIdx.x;
    const int w = tid >> 6, lane = tid & 63;
    const int q = lane >> 4, l15 = lane & 15;
    const int row0 = blockIdx.x * 64 + w * 16;
    const int ar = min(row0 + l15, N_NODES - 1);
    const float* xp = x + (size_t)ar * F_IN + q * 8;
    f32x4 acc[8];
#pragma unroll
    for (int nt = 0; nt < 8; ++nt) acc[nt] = (f32x4){0.f, 0.f, 0.f, 0.f};
#pragma unroll
    for (int ks = 0; ks < 2; ++ks) {
        const float4 v0 = *(const float4*)(xp + ks * 32);
        const float4 v1 = *(const float4*)(xp + ks * 32 + 4);
        unsigned int u[4] = {pack2(v0.x, v0.y), pack2(v0.z, v0.w),
                             pack2(v1.x, v1.y), pack2(v1.z, v1.w)};
        short8 a; __builtin_memcpy(&a, u, 16);
#pragma unroll
        for (int nt = 0; nt < 8; ++nt) {
            const short8 bf = *(const short8*)(wpe + (((ks << 3) + nt) * 64 + lane) * 8);
            acc[nt] = __builtin_amdgcn_mfma_f32_16x16x32_bf16(a, bf, acc[nt], 0, 0, 0);
        }
    }
    const int rowb = row0 + q * 4;
#pragma unroll
    for (int nt = 0; nt < 8; ++nt) {
        const float bias = b[nt * 16 + l15];
        const int cc = nt * 16 + l15;
#pragma unroll
        for (int reg = 0; reg < 4; ++reg) {
            const int r = rowb + reg;
            if (r < N_NODES)
                hb[(size_t)r * HID + cc] = (unsigned short)f2bf(acc[nt][reg] + bias);
        }
    }
}

// ---------------------------------------------------------------------------
// BN apply pass (layers 1,2): h' = relu(BN(z)) materialized ONCE per node.
// 800000 threads (3125 blocks), one uint4 (8 bf16 feats) per thread.
// ---------------------------------------------------------------------------
__global__ __launch_bounds__(256) void k_bn(const unsigned short* __restrict__ z,
                                            const float* __restrict__ bnst,
                                            const float* __restrict__ gamma,
                                            const float* __restrict__ beta,
                                            unsigned short* __restrict__ hb2) {
    const int idx = blockIdx.x * 256 + threadIdx.x;   // 3125*256 = 800000 exact
    const int f0 = (idx * 8) & 127;
    const float invN = 1.0f / (float)N_NODES;
    uint4 v = *(const uint4*)(z + (size_t)idx * 8);
    const unsigned int* u = (const unsigned int*)&v;
    unsigned int o[4];
#pragma unroll
    for (int p = 0; p < 4; ++p) {
        const int f = f0 + 2 * p;
        const float m0 = bnst[f] * invN;
        const float m1 = bnst[f + 1] * invN;
        const float v0 = fmaxf(bnst[128 + f] * invN - m0 * m0, 0.f);
        const float v1 = fmaxf(bnst[128 + f + 1] * invN - m1 * m1, 0.f);
        const float r0 = rsqrtf(v0 + BN_EPS), r1 = rsqrtf(v1 + BN_EPS);
        const float sc0 = gamma[f] * r0, sc1 = gamma[f + 1] * r1;
        const float sh0 = fmaf(-m0, sc0, beta[f]);
        const float sh1 = fmaf(-m1, sc1, beta[f + 1]);
        const float a = fmaxf(fmaf(bfl(u[p]), sc0, sh0), 0.f);
        const float b = fmaxf(fmaf(bfh(u[p]), sc1, sh1), 0.f);
        o[p] = pack2(a, b);
    }
    *(uint4*)(hb2 + (size_t)idx * 8) = make_uint4(o[0], o[1], o[2], o[3]);
}

// ---------------------------------------------------------------------------
// GINE aggregation v14: PERSISTENT waves, v11 per-node body, VGPR <= 64.
// Grid = 2048 blocks x 4 waves = 8192 waves; __launch_bounds__(256, 8)
// caps VGPR at 64 so all 8 blocks/CU are resident -> occupancy goes to the
// hardware cap and cross-WAVE overlap (8 waves/SIMD) hides gather latency;
// the kernel becomes VALU-throughput-bound. Each wave strides nodes by
// 8192 (~6 nodes). Per-node math identical to v11 (same epilogue order).
// ---------------------------------------------------------------------------
__global__ __launch_bounds__(256, 8) void k_agg(const unsigned short* __restrict__ hrow,
                                                const int* __restrict__ src_s,
                                                const uint4* __restrict__ eattr_h,
                                                const unsigned short* __restrict__ wekf,
                                                const int* __restrict__ row_ptr,
                                                unsigned int* __restrict__ zb32) {
    const int lane = threadIdx.x & 63;
    const int wv = threadIdx.x >> 6;
    const int q = lane >> 4, l15 = lane & 15;
    const int f0 = l15 * 8;                   // this lane's 8 contiguous features

    // edge-weight B-frags for this layer (bias folded at k==16); L2-hot
    half8 Bf[8];
#pragma unroll
    for (int nt = 0; nt < 8; ++nt) {
        uint4 u = *(const uint4*)(wekf + (nt * 64 + lane) * 8);
        __builtin_memcpy(&Bf[nt], &u, 16);
    }

    const int w0 = blockIdx.x * 4 + wv;       // 2048*4 = 8192 waves

    for (int n = w0; n < N_NODES; n += 8192) {
        const int base = __builtin_amdgcn_readfirstlane(row_ptr[n]);
        const int deg  = __builtin_amdgcn_readfirstlane(row_ptr[n + 1]) - base;

        float accf[8];
#pragma unroll
        for (int j = 0; j < 8; ++j) accf[j] = 0.f;

        if (deg > 0) {
            const int ntile = (deg + 15) >> 4;
            for (int t = 0; t < ntile; ++t) {
                const int e0 = t * 16;
                // A fragment: row = edge (l15), k = 8q+j. q<2: attrs; q==2: 1.0@k=16.
                uint4 au = make_uint4(0u, 0u, 0u, 0u);
                if (q < 2) {
                    const int ea = min(e0 + l15, deg - 1);
                    au = eattr_h[(size_t)(base + ea) * 2 + q];
                } else if (q == 2) {
                    au.x = 0x3C00u;           // f16 1.0 -> bias row
                }
                half8 Af; __builtin_memcpy(&Af, &au, 16);

                // srcs + h gathers for this lane's 4 edges (one dwordx4 each)
                int sv[4];
#pragma unroll
                for (int r = 0; r < 4; ++r)
                    sv[r] = src_s[base + min(e0 + q * 4 + r, deg - 1)];
                uint4 hg[4];
#pragma unroll
                for (int r = 0; r < 4; ++r)
                    hg[r] = *(const uint4*)(hrow + (size_t)sv[r] * HID + f0);

                // e + bias for 16 edges x 8 feats/lane on the matrix pipe
                f32x4 acc[8];
#pragma unroll
                for (int nt = 0; nt < 8; ++nt) {
                    acc[nt] = (f32x4){0.f, 0.f, 0.f, 0.f};
                    acc[nt] = __builtin_amdgcn_mfma_f32_16x16x32_f16(Af, Bf[nt], acc[nt], 0, 0, 0);
                }

                // masked accumulate: accf += m * relu(h_src + e)
#pragma unroll
                for (int r = 0; r < 4; ++r) {
                    const float m = (e0 + q * 4 + r < deg) ? 1.f : 0.f;
                    const unsigned int* hu = (const unsigned int*)&hg[r];
#pragma unroll
                    for (int p = 0; p < 4; ++p) {
                        accf[2 * p]     = fmaf(m, fmaxf(bfl(hu[p]) + acc[2 * p][r],     0.f), accf[2 * p]);
                        accf[2 * p + 1] = fmaf(m, fmaxf(bfh(hu[p]) + acc[2 * p + 1][r], 0.f), accf[2 * p + 1]);
                    }
                }
            }
        }

        // reduce the 4 q-groups (edges 4q+r) -> full aggregate per feature
#pragma unroll
        for (int j = 0; j < 8; ++j) {
            accf[j] += __shfl_xor(accf[j], 16, 64);
            accf[j] += __shfl_xor(accf[j], 32, 64);
        }

        // self term (raw h') + packed bf16 write (16 lanes x 16B = 256B row)
        if (q == 0) {
            const uint4 hs = *(const uint4*)(hrow + (size_t)n * HID + f0);
            const unsigned int* hu = (const unsigned int*)&hs;
            unsigned int o[4];
#pragma unroll
            for (int p = 0; p < 4; ++p)
                o[p] = pack2(bfl(hu[p]) + accf[2 * p], bfh(hu[p]) + accf[2 * p + 1]);
            *(uint4*)(zb32 + (size_t)n * 64 + l15 * 4) = make_uint4(o[0], o[1], o[2], o[3]);
        }
    }
}

// ---------------------------------------------------------------------------
// Fused node MLP via bf16 MFMA (16x16x32): z2b = bf16(relu(z@W1+b1)@W2+b2),
// plus BN sum/sumsq partials (fp32, from accumulators).
// ---------------------------------------------------------------------------
#define Z1LD 136

__global__ __launch_bounds__(256, 3) void k_mlp(const unsigned short* __restrict__ zb,
                                                const unsigned short* __restrict__ w1p,
                                                const float* __restrict__ b1,
                                                const unsigned short* __restrict__ w2p,
                                                const float* __restrict__ b2,
                                                unsigned short* __restrict__ z2b,
                                                float* __restrict__ bn) {
    __shared__ unsigned short z1s[64 * Z1LD];
    __shared__ float redA[512];
    __shared__ float redB[512];
    const int tid = threadIdx.x;
    const int w = tid >> 6, lane = tid & 63;
    const int q = lane >> 4, l15 = lane & 15;
    const int row0 = blockIdx.x * 64 + w * 16;

    const int ar = min(row0 + l15, N_NODES - 1);
    const unsigned short* aptr = zb + (size_t)ar * HID + q * 8;

    f32x4 acc[8];
#pragma unroll
    for (int nt = 0; nt < 8; ++nt) acc[nt] = (f32x4){0.f, 0.f, 0.f, 0.f};

#pragma unroll
    for (int ks = 0; ks < 4; ++ks) {
        const short8 a = *(const short8*)(aptr + ks * 32);
#pragma unroll
        for (int nt = 0; nt < 8; ++nt) {
            const short8 b = *(const short8*)(w1p + (((ks << 3) + nt) * 64 + lane) * 8);
            acc[nt] = __builtin_amdgcn_mfma_f32_16x16x32_bf16(a, b, acc[nt], 0, 0, 0);
        }
    }
    {
        const int lr0 = w * 16 + q * 4;
#pragma unroll
        for (int nt = 0; nt < 8; ++nt) {
            const float bias = b1[nt * 16 + l15];
            const int cc = nt * 16 + l15;
#pragma unroll
            for (int reg = 0; reg < 4; ++reg) {
                const float v = fmaxf(acc[nt][reg] + bias, 0.f);
                z1s[(lr0 + reg) * Z1LD + cc] = (unsigned short)f2bf(v);
            }
        }
    }
#pragma unroll
    for (int nt = 0; nt < 8; ++nt) acc[nt] = (f32x4){0.f, 0.f, 0.f, 0.f};
    const unsigned short* a2p = &z1s[(w * 16 + l15) * Z1LD + q * 8];
#pragma unroll
    for (int ks = 0; ks < 4; ++ks) {
        const short8 a = *(const short8*)(a2p + ks * 32);
#pragma unroll
        for (int nt = 0; nt < 8; ++nt) {
            const short8 b = *(const short8*)(w2p + (((ks << 3) + nt) * 64 + lane) * 8);
            acc[nt] = __builtin_amdgcn_mfma_f32_16x16x32_bf16(a, b, acc[nt], 0, 0, 0);
        }
    }
    float s[8], sq[8];
    const int rowb = row0 + q * 4;
#pragma unroll
    for (int nt = 0; nt < 8; ++nt) {
        const float bias = b2[nt * 16 + l15];
        const int cc = nt * 16 + l15;
        float ls = 0.f, lq = 0.f;
#pragma unroll
        for (int reg = 0; reg < 4; ++reg) {
            const int r = rowb + reg;
            const float v = acc[nt][reg] + bias;
            if (r < N_NODES) {
                z2b[(size_t)r * HID + cc] = (unsigned short)f2bf(v);
                ls += v;
                lq = fmaf(v, v, lq);
            }
        }
        s[nt] = ls; sq[nt] = lq;
    }
#pragma unroll
    for (int nt = 0; nt < 8; ++nt) {
        s[nt] += __shfl_xor(s[nt], 16, 64);
        s[nt] += __shfl_xor(s[nt], 32, 64);
        sq[nt] += __shfl_xor(sq[nt], 16, 64);
        sq[nt] += __shfl_xor(sq[nt], 32, 64);
    }
    if (lane < 16) {
#pragma unroll
        for (int nt = 0; nt < 8; ++nt) {
            redA[w * 128 + nt * 16 + lane] = s[nt];
            redB[w * 128 + nt * 16 + lane] = sq[nt];
        }
    }
    __syncthreads();
    if (tid < 128) {
        float t = redA[tid] + redA[128 + tid] + redA[256 + tid] + redA[384 + tid];
        atomicAdd(&bn[tid], t);
    } else {
        const int c = tid - 128;
        float t = redB[c] + redB[128 + c] + redB[256 + c] + redB[384 + c];
        atomicAdd(&bn[128 + c], t);
    }
}

// ---------------------------------------------------------------------------
// Global add pool (batch sorted), with fused BN+ReLU of the last layer.
// ---------------------------------------------------------------------------
__global__ void k_pool(const unsigned short* __restrict__ z2b, const int* __restrict__ batch,
                       const float* __restrict__ bnst, const float* __restrict__ gamma,
                       const float* __restrict__ beta, float* __restrict__ g) {
    const int f = threadIdx.x;            // 128 threads
    const float invN = 1.0f / (float)N_NODES;
    const float m = bnst[f] * invN;
    const float var = fmaxf(bnst[128 + f] * invN - m * m, 0.f);
    const float r = rsqrtf(var + BN_EPS);
    const float sc = gamma[f] * r;
    const float sh = fmaf(-m, sc, beta[f]);

    const int n0 = blockIdx.x * 128;
    const int nend = min(n0 + 128, N_NODES);
    float acc = 0.f;
    int cur = batch[n0];
    for (int n = n0; n < nend; ++n) {
        const int bb = batch[n];
        if (bb != cur) {
            atomicAdd(&g[cur * HID + f], acc);
            acc = 0.f;
            cur = bb;
        }
        const float raw = bfl((unsigned int)z2b[n * HID + f]);
        acc += fmaxf(fmaf(raw, sc, sh), 0.f);
    }
    atomicAdd(&g[cur * HID + f], acc);
}

// ---------------------------------------------------------------------------
// Head
// ---------------------------------------------------------------------------
__global__ void k_head1(const float* __restrict__ g, const float* __restrict__ W,
                        const float* __restrict__ b, float* __restrict__ g1) {
    const int idx = blockIdx.x * 256 + threadIdx.x;   // 32*256 = 8192
    const int r = idx >> 7, c = idx & 127;
    float acc = b[c];
    for (int k = 0; k < 128; ++k) acc = fmaf(g[r * HID + k], W[k * HID + c], acc);
    g1[idx] = fmaxf(acc, 0.f);
}

__global__ void k_head2(const float* __restrict__ g1, const float* __restrict__ W,
                        const float* __restrict__ b, float* __restrict__ out) {
    const int idx = threadIdx.x;          // 128
    const int r = idx >> 1, c = idx & 1;
    float acc = b[c];
    for (int k = 0; k < 128; ++k) acc = fmaf(g1[r * HID + k], W[k * 2 + c], acc);
    out[idx] = acc;
}

// ---------------------------------------------------------------------------
// Launch
// ---------------------------------------------------------------------------
extern "C" void kernel_launch(void* const* d_in, const int* in_sizes, int n_in,
                              void* d_out, int out_size, void* d_ws, size_t ws_size,
                              hipStream_t stream) {
    const float* x     = (const float*)d_in[0];
    const int*   ei    = (const int*)d_in[1];
    const float* eattr = (const float*)d_in[2];
    const int*   batch = (const int*)d_in[3];
    const float* encW  = (const float*)d_in[4];
    const float* encb  = (const float*)d_in[5];
    const float* eW    = (const float*)d_in[6];
    const float* eb    = (const float*)d_in[7];
    const float* W1    = (const float*)d_in[8];
    const float* b1    = (const float*)d_in[9];
    const float* W2    = (const float*)d_in[10];
    const float* b2    = (const float*)d_in[11];
    const float* gam   = (const float*)d_in[12];
    const float* bet   = (const float*)d_in[13];
    const float* hW1   = (const float*)d_in[14];
    const float* hb1   = (const float*)d_in[15];
    const float* hW2   = (const float*)d_in[16];
    const float* hb2w  = (const float*)d_in[17];
    float* out = (float*)d_out;

    // workspace layout (float-sized slots)
    float* ws = (float*)d_ws;
    unsigned short* z2b = (unsigned short*)ws;              // [0, 3.2M) 6.4M u16
    float* bn  = ws + 3200000;              // 256
    float* g   = ws + 3200256;              // 8,192
    float* g1  = ws + 3208448;              // 8,192
    unsigned short* hb  = (unsigned short*)(ws + 3216640);  // 6.4M u16 (encoder out)
    unsigned int* zb32  = (unsigned int*)(ws + 6416640);    // 3.2M u32
    unsigned short* hb2 = (unsigned short*)(ws + 9616640);  // 6.4M u16 (BN-applied h')
    unsigned short* wekf = (unsigned short*)(ws + 12816640);// 12,288 u16
    unsigned short* wp  = (unsigned short*)(ws + 12822784); // 98,304 u16
    unsigned short* wpe = (unsigned short*)(ws + 12871936); // 8,192 u16
    int* row_ptr = (int*)(ws + 12876032);   // 50,001
    int* cursor  = row_ptr + N_NODES + 1;   // 50,000
    int* elist   = cursor + N_NODES;        // 640,000 (unused, slot kept)
    int* bsums   = elist + N_EDGES;         // 256
    int* src_s   = bsums + 256;             // 640,000 (ends 14,256,289)
    uint4* eattr_h = (uint4*)(ws + 14256292);               // 5.12M floats, 16B aligned

    const int* esrc = ei;
    const int* edst = ei + N_EDGES;

    // CSR build + fused edge materialization (per call)
    hipMemsetAsync(row_ptr, 0, (N_NODES + 1) * sizeof(int), stream);
    k_hist<<<N_EDGES / 256, 256, 0, stream>>>(edst, row_ptr);
    k_blockred<<<196, 256, 0, stream>>>(row_ptr, bsums);
    k_scan_bsums<<<1, 256, 0, stream>>>(bsums, 196);
    k_scan_blocks<<<196, 256, 0, stream>>>(row_ptr, bsums, cursor);
    k_fill<<<N_EDGES / 256, 256, 0, stream>>>(esrc, edst, eattr, cursor, src_s, eattr_h);

    // merged weight packing (edge bias folded into wekf k==16 row)
    k_pack<<<64, 256, 0, stream>>>(W1, W2, encW, eW, eb, wp, wpe, wekf);

    // encoder -> bf16 h (MFMA, reads fp32 x directly)
    k_encm<<<782, 256, 0, stream>>>(x, wpe, encb, hb);

    for (int l = 0; l < N_LAYERS; ++l) {
        const unsigned short* hrow;
        if (l == 0) {
            hrow = hb;
        } else {
            // materialize h' = relu(BN(z_prev)) once per node
            k_bn<<<3125, 256, 0, stream>>>(z2b, bn, gam + (l - 1) * HID,
                                           bet + (l - 1) * HID, hb2);
            hrow = hb2;
        }
        k_agg<<<2048, 256, 0, stream>>>(hrow, src_s, eattr_h,
                                        wekf + (size_t)l * 4096, row_ptr, zb32);
        hipMemsetAsync(bn, 0, 256 * sizeof(float), stream);
        k_mlp<<<782, 256, 0, stream>>>((const unsigned short*)zb32,
                                       wp + (size_t)l * 16384, b1 + l * HID,
                                       wp + (size_t)(3 + l) * 16384, b2 + l * HID,
                                       z2b, bn);
    }

    hipMemsetAsync(g, 0, NUM_GRAPHS * HID * sizeof(float), stream);
    k_pool<<<391, 128, 0, stream>>>(z2b, batch, bn, gam + 2 * HID, bet + 2 * HID, g);
    k_head1<<<32, 256, 0, stream>>>(g, hW1, hb1, g1);
    k_head2<<<1, 128, 0, stream>>>(g1, hW2, hb2w, out);
}

// Round 6
// 501.694 us; speedup vs baseline: 1.4394x; 1.4394x over previous
//
#include <hip/hip_runtime.h>
#include <hip/hip_bf16.h>

// Problem constants (from reference)
#define N_NODES 50000
#define N_EDGES 640000
#define F_IN 64
#define EDGE_DIM 16
#define HID 128
#define N_LAYERS 3
#define NUM_GRAPHS 64
#define BN_EPS 1e-5f

typedef __attribute__((ext_vector_type(8))) short short8;    // 8 bf16 (4 VGPRs)
typedef __attribute__((ext_vector_type(4))) float f32x4;     // MFMA acc
typedef __attribute__((ext_vector_type(2))) __fp16 half2v;   // packed f16 pair
typedef __attribute__((ext_vector_type(8))) __fp16 half8;    // 8 f16 (4 VGPRs) MFMA frag

// bf16 <-> f32 helpers (manual, RNE on pack)
__device__ __forceinline__ float bfl(unsigned int u) {
    unsigned int v = u << 16; float f; __builtin_memcpy(&f, &v, 4); return f;
}
__device__ __forceinline__ float bfh(unsigned int u) {
    unsigned int v = u & 0xffff0000u; float f; __builtin_memcpy(&f, &v, 4); return f;
}
__device__ __forceinline__ unsigned int f2bf(float f) {
    unsigned int v; __builtin_memcpy(&v, &f, 4);
    v += 0x7fffu + ((v >> 16) & 1u);
    return v >> 16;
}
__device__ __forceinline__ unsigned int pack2(float lo, float hi) {
    return f2bf(lo) | (f2bf(hi) << 16);
}
__device__ __forceinline__ unsigned int pkh(float a, float b) {
    half2v h = __builtin_amdgcn_cvt_pkrtz(a, b);
    unsigned int u; __builtin_memcpy(&u, &h, 4); return u;
}

// ---------------------------------------------------------------------------
// CSR build
// ---------------------------------------------------------------------------
__global__ void k_hist(const int* __restrict__ dst, int* __restrict__ deg) {
    int e = blockIdx.x * 256 + threadIdx.x;   // grid exact: 2500*256 = 640000
    atomicAdd(&deg[dst[e]], 1);
}

__global__ void k_blockred(const int* __restrict__ deg, int* __restrict__ bsums) {
    __shared__ int s[256];
    int i = blockIdx.x * 256 + threadIdx.x;
    int v = (i < N_NODES) ? deg[i] : 0;
    s[threadIdx.x] = v;
    __syncthreads();
    for (int off = 128; off > 0; off >>= 1) {
        if (threadIdx.x < off) s[threadIdx.x] += s[threadIdx.x + off];
        __syncthreads();
    }
    if (threadIdx.x == 0) bsums[blockIdx.x] = s[0];
}

// parallel exclusive scan of block sums (nb <= 256, one block)
__global__ void k_scan_bsums(int* __restrict__ bsums, int nb) {
    __shared__ int s[256];
    const int tid = threadIdx.x;
    const int v = (tid < nb) ? bsums[tid] : 0;
    s[tid] = v;
    __syncthreads();
    for (int off = 1; off < 256; off <<= 1) {
        int t = 0;
        if (tid >= off) t = s[tid - off];
        __syncthreads();
        s[tid] += t;
        __syncthreads();
    }
    if (tid < nb) bsums[tid] = s[tid] - v;
}

__global__ void k_scan_blocks(int* __restrict__ deg_rowptr, const int* __restrict__ bsums,
                              int* __restrict__ cursor) {
    __shared__ int s[256];
    int tid = threadIdx.x;
    int i = blockIdx.x * 256 + tid;
    int v = (i < N_NODES) ? deg_rowptr[i] : 0;
    s[tid] = v;
    __syncthreads();
    for (int off = 1; off < 256; off <<= 1) {
        int t = 0;
        if (tid >= off) t = s[tid - off];
        __syncthreads();
        s[tid] += t;
        __syncthreads();
    }
    int excl = s[tid] - v + bsums[blockIdx.x];
    if (i < N_NODES) {
        deg_rowptr[i] = excl;
        cursor[i] = excl;
    }
    if (i == N_NODES - 1) deg_rowptr[N_NODES] = N_EDGES;
}

// ---------------------------------------------------------------------------
// Fused fill + edge materialization: reads esrc/edst/eattr COALESCED in
// original edge order, one atomicAdd for the CSR slot, scatters src_s (4B)
// and f16-packed eattr (32B) to the slot.
// ---------------------------------------------------------------------------
__global__ __launch_bounds__(256) void k_fill(const int* __restrict__ esrc,
                                              const int* __restrict__ edst,
                                              const float* __restrict__ eattr,
                                              int* __restrict__ cursor,
                                              int* __restrict__ src_s,
                                              uint4* __restrict__ eattr_h) {
    const int e = blockIdx.x * 256 + threadIdx.x;   // exact: 2500*256 = 640000
    const int s = esrc[e];
    const int d = edst[e];
    const float* ep = eattr + (size_t)e * EDGE_DIM;
    const float4 a0 = *(const float4*)ep;
    const float4 a1 = *(const float4*)(ep + 4);
    const float4 a2 = *(const float4*)(ep + 8);
    const float4 a3 = *(const float4*)(ep + 12);
    const int p = atomicAdd(&cursor[d], 1);
    src_s[p] = s;
    eattr_h[p * 2] = make_uint4(pkh(a0.x, a0.y), pkh(a0.z, a0.w),
                                pkh(a1.x, a1.y), pkh(a1.z, a1.w));
    eattr_h[p * 2 + 1] = make_uint4(pkh(a2.x, a2.y), pkh(a2.z, a2.w),
                                    pkh(a3.x, a3.y), pkh(a3.z, a3.w));
}

// ---------------------------------------------------------------------------
// Merged weight packing: [0,12288) = W1/W2 MFMA B-frags, [12288,13312) =
// enc_W B-frags, [13312,16384) = edge-weight f16 MFMA B-frags (wekf).
// wekf layout per layer: 8 n-frags x 64 lanes x 8 halves. B column c of frag
// nt maps to feature 8*c+nt (so a lane's 8 output features are contiguous).
// k = 8*(lane>>4)+j; k<16 -> W[k][f]; k==16 -> bias[f] (A supplies 1.0 there).
// ---------------------------------------------------------------------------
__global__ void k_pack(const float* __restrict__ W1, const float* __restrict__ W2,
                       const float* __restrict__ encW, const float* __restrict__ eW,
                       const float* __restrict__ eb2,
                       unsigned short* __restrict__ wp, unsigned short* __restrict__ wpe,
                       unsigned short* __restrict__ wekf) {
    const int t = blockIdx.x * 256 + threadIdx.x;   // 64*256 = 16384 exact
    if (t < 12288) {
        const int mat = t >> 11;
        const int r = t & 2047;
        const int kstep = r >> 9;
        const int ntile = (r >> 6) & 7;
        const int lane = r & 63;
        const float* W = (mat < 3) ? (W1 + mat * 16384) : (W2 + (mat - 3) * 16384);
        const int kbase = kstep * 32 + ((lane >> 4) << 3);
        const int n = ntile * 16 + (lane & 15);
        unsigned int o[4];
#pragma unroll
        for (int jj = 0; jj < 4; ++jj)
            o[jj] = pack2(W[(kbase + 2 * jj) * HID + n], W[(kbase + 2 * jj + 1) * HID + n]);
        *(uint4*)(wp + (size_t)mat * 16384 + (((kstep << 3) + ntile) * 64 + lane) * 8) =
            make_uint4(o[0], o[1], o[2], o[3]);
    } else if (t < 13312) {
        const int r = t - 12288;
        const int kstep = r >> 9;
        const int ntile = (r >> 6) & 7;
        const int lane = r & 63;
        const int kbase = kstep * 32 + ((lane >> 4) << 3);
        const int n = ntile * 16 + (lane & 15);
        unsigned int o[4];
#pragma unroll
        for (int jj = 0; jj < 4; ++jj)
            o[jj] = pack2(encW[(kbase + 2 * jj) * HID + n], encW[(kbase + 2 * jj + 1) * HID + n]);
        *(uint4*)(wpe + (((kstep << 3) + ntile) * 64 + lane) * 8) =
            make_uint4(o[0], o[1], o[2], o[3]);
    } else {
        const int r = t - 13312;                    // 0..3071, 4 halves each
        const int l = r >> 10;
        const int rr = r & 1023;
        const int nt = rr >> 7;
        const int lane = (rr >> 1) & 63;
        const int hf = rr & 1;
        const int qq = lane >> 4;
        const int f = ((lane & 15) << 3) + nt;      // permuted column -> feature
        float v[4];
#pragma unroll
        for (int j = 0; j < 4; ++j) {
            const int k = (qq << 3) + (hf << 2) + j;
            v[j] = (k < 16) ? eW[(l * EDGE_DIM + k) * HID + f]
                            : ((k == 16) ? eb2[l * HID + f] : 0.f);
        }
        *(uint2*)(wekf + (((l * 8 + nt) * 64 + lane) * 8) + (hf << 2)) =
            make_uint2(pkh(v[0], v[1]), pkh(v[2], v[3]));
    }
}

// ---------------------------------------------------------------------------
// Encoder via MFMA: hb = bf16(x @ enc_W + enc_b), reads fp32 x directly.
// ---------------------------------------------------------------------------
__global__ __launch_bounds__(256, 3) void k_encm(const float* __restrict__ x,
                                                 const unsigned short* __restrict__ wpe,
                                                 const float* __restrict__ b,
                                                 unsigned short* __restrict__ hb) {
    const int tid = threadIdx.x;
    const int w = tid >> 6, lane = tid & 63;
    const int q = lane >> 4, l15 = lane & 15;
    const int row0 = blockIdx.x * 64 + w * 16;
    const int ar = min(row0 + l15, N_NODES - 1);
    const float* xp = x + (size_t)ar * F_IN + q * 8;
    f32x4 acc[8];
#pragma unroll
    for (int nt = 0; nt < 8; ++nt) acc[nt] = (f32x4){0.f, 0.f, 0.f, 0.f};
#pragma unroll
    for (int ks = 0; ks < 2; ++ks) {
        const float4 v0 = *(const float4*)(xp + ks * 32);
        const float4 v1 = *(const float4*)(xp + ks * 32 + 4);
        unsigned int u[4] = {pack2(v0.x, v0.y), pack2(v0.z, v0.w),
                             pack2(v1.x, v1.y), pack2(v1.z, v1.w)};
        short8 a; __builtin_memcpy(&a, u, 16);
#pragma unroll
        for (int nt = 0; nt < 8; ++nt) {
            const short8 bf = *(const short8*)(wpe + (((ks << 3) + nt) * 64 + lane) * 8);
            acc[nt] = __builtin_amdgcn_mfma_f32_16x16x32_bf16(a, bf, acc[nt], 0, 0, 0);
        }
    }
    const int rowb = row0 + q * 4;
#pragma unroll
    for (int nt = 0; nt < 8; ++nt) {
        const float bias = b[nt * 16 + l15];
        const int cc = nt * 16 + l15;
#pragma unroll
        for (int reg = 0; reg < 4; ++reg) {
            const int r = rowb + reg;
            if (r < N_NODES)
                hb[(size_t)r * HID + cc] = (unsigned short)f2bf(acc[nt][reg] + bias);
        }
    }
}

// ---------------------------------------------------------------------------
// BN apply pass (layers 1,2): h' = relu(BN(z)) materialized ONCE per node.
// 800000 threads (3125 blocks), one uint4 (8 bf16 feats) per thread.
// ---------------------------------------------------------------------------
__global__ __launch_bounds__(256) void k_bn(const unsigned short* __restrict__ z,
                                            const float* __restrict__ bnst,
                                            const float* __restrict__ gamma,
                                            const float* __restrict__ beta,
                                            unsigned short* __restrict__ hb2) {
    const int idx = blockIdx.x * 256 + threadIdx.x;   // 3125*256 = 800000 exact
    const int f0 = (idx * 8) & 127;
    const float invN = 1.0f / (float)N_NODES;
    uint4 v = *(const uint4*)(z + (size_t)idx * 8);
    const unsigned int* u = (const unsigned int*)&v;
    unsigned int o[4];
#pragma unroll
    for (int p = 0; p < 4; ++p) {
        const int f = f0 + 2 * p;
        const float m0 = bnst[f] * invN;
        const float m1 = bnst[f + 1] * invN;
        const float v0 = fmaxf(bnst[128 + f] * invN - m0 * m0, 0.f);
        const float v1 = fmaxf(bnst[128 + f + 1] * invN - m1 * m1, 0.f);
        const float r0 = rsqrtf(v0 + BN_EPS), r1 = rsqrtf(v1 + BN_EPS);
        const float sc0 = gamma[f] * r0, sc1 = gamma[f + 1] * r1;
        const float sh0 = fmaf(-m0, sc0, beta[f]);
        const float sh1 = fmaf(-m1, sc1, beta[f + 1]);
        const float a = fmaxf(fmaf(bfl(u[p]), sc0, sh0), 0.f);
        const float b = fmaxf(fmaf(bfh(u[p]), sc1, sh1), 0.f);
        o[p] = pack2(a, b);
    }
    *(uint4*)(hb2 + (size_t)idx * 8) = make_uint4(o[0], o[1], o[2], o[3]);
}

// ---------------------------------------------------------------------------
// GINE aggregation v15: PERSISTENT waves at the NATURAL VGPR tier.
// Body = v11 (no spills at its ~84-VGPR natural footprint). Grid = 1024
// blocks = exactly one residency cohort at 4 blocks/CU (84 VGPR -> 4
// waves/SIMD tier). __launch_bounds__(256, 4) caps VGPR at 128 (no spill;
// R5's (256,8) forced VGPR<=64 and spilled ~420MB of scratch traffic).
// Each wave strides nodes by 4096 (~12 nodes). All waves resident for the
// kernel's whole life -> no launch-rate cap, no cohort tail.
// ---------------------------------------------------------------------------
__global__ __launch_bounds__(256, 4) void k_agg(const unsigned short* __restrict__ hrow,
                                                const int* __restrict__ src_s,
                                                const uint4* __restrict__ eattr_h,
                                                const unsigned short* __restrict__ wekf,
                                                const int* __restrict__ row_ptr,
                                                unsigned int* __restrict__ zb32) {
    const int lane = threadIdx.x & 63;
    const int wv = threadIdx.x >> 6;
    const int q = lane >> 4, l15 = lane & 15;
    const int f0 = l15 * 8;                   // this lane's 8 contiguous features

    // edge-weight B-frags for this layer (bias folded at k==16); L2-hot
    half8 Bf[8];
#pragma unroll
    for (int nt = 0; nt < 8; ++nt) {
        uint4 u = *(const uint4*)(wekf + (nt * 64 + lane) * 8);
        __builtin_memcpy(&Bf[nt], &u, 16);
    }

    const int w0 = blockIdx.x * 4 + wv;       // 1024*4 = 4096 waves

    for (int n = w0; n < N_NODES; n += 4096) {
        const int base = __builtin_amdgcn_readfirstlane(row_ptr[n]);
        const int deg  = __builtin_amdgcn_readfirstlane(row_ptr[n + 1]) - base;

        float accf[8];
#pragma unroll
        for (int j = 0; j < 8; ++j) accf[j] = 0.f;

        if (deg > 0) {
            const int ntile = (deg + 15) >> 4;
            for (int t = 0; t < ntile; ++t) {
                const int e0 = t * 16;
                // A fragment: row = edge (l15), k = 8q+j. q<2: attrs; q==2: 1.0@k=16.
                uint4 au = make_uint4(0u, 0u, 0u, 0u);
                if (q < 2) {
                    const int ea = min(e0 + l15, deg - 1);
                    au = eattr_h[(size_t)(base + ea) * 2 + q];
                } else if (q == 2) {
                    au.x = 0x3C00u;           // f16 1.0 -> bias row
                }
                half8 Af; __builtin_memcpy(&Af, &au, 16);

                // srcs + h gathers for this lane's 4 edges (one dwordx4 each)
                int sv[4];
#pragma unroll
                for (int r = 0; r < 4; ++r)
                    sv[r] = src_s[base + min(e0 + q * 4 + r, deg - 1)];
                uint4 hg[4];
#pragma unroll
                for (int r = 0; r < 4; ++r)
                    hg[r] = *(const uint4*)(hrow + (size_t)sv[r] * HID + f0);

                // e + bias for 16 edges x 8 feats/lane on the matrix pipe
                f32x4 acc[8];
#pragma unroll
                for (int nt = 0; nt < 8; ++nt) {
                    acc[nt] = (f32x4){0.f, 0.f, 0.f, 0.f};
                    acc[nt] = __builtin_amdgcn_mfma_f32_16x16x32_f16(Af, Bf[nt], acc[nt], 0, 0, 0);
                }

                // masked accumulate: accf += m * relu(h_src + e)
#pragma unroll
                for (int r = 0; r < 4; ++r) {
                    const float m = (e0 + q * 4 + r < deg) ? 1.f : 0.f;
                    const unsigned int* hu = (const unsigned int*)&hg[r];
#pragma unroll
                    for (int p = 0; p < 4; ++p) {
                        accf[2 * p]     = fmaf(m, fmaxf(bfl(hu[p]) + acc[2 * p][r],     0.f), accf[2 * p]);
                        accf[2 * p + 1] = fmaf(m, fmaxf(bfh(hu[p]) + acc[2 * p + 1][r], 0.f), accf[2 * p + 1]);
                    }
                }
            }
        }

        // reduce the 4 q-groups (edges 4q+r) -> full aggregate per feature
#pragma unroll
        for (int j = 0; j < 8; ++j) {
            accf[j] += __shfl_xor(accf[j], 16, 64);
            accf[j] += __shfl_xor(accf[j], 32, 64);
        }

        // self term (raw h') + packed bf16 write (16 lanes x 16B = 256B row)
        if (q == 0) {
            const uint4 hs = *(const uint4*)(hrow + (size_t)n * HID + f0);
            const unsigned int* hu = (const unsigned int*)&hs;
            unsigned int o[4];
#pragma unroll
            for (int p = 0; p < 4; ++p)
                o[p] = pack2(bfl(hu[p]) + accf[2 * p], bfh(hu[p]) + accf[2 * p + 1]);
            *(uint4*)(zb32 + (size_t)n * 64 + l15 * 4) = make_uint4(o[0], o[1], o[2], o[3]);
        }
    }
}

// ---------------------------------------------------------------------------
// Fused node MLP via bf16 MFMA (16x16x32): z2b = bf16(relu(z@W1+b1)@W2+b2),
// plus BN sum/sumsq partials (fp32, from accumulators).
// ---------------------------------------------------------------------------
#define Z1LD 136

__global__ __launch_bounds__(256, 3) void k_mlp(const unsigned short* __restrict__ zb,
                                                const unsigned short* __restrict__ w1p,
                                                const float* __restrict__ b1,
                                                const unsigned short* __restrict__ w2p,
                                                const float* __restrict__ b2,
                                                unsigned short* __restrict__ z2b,
                                                float* __restrict__ bn) {
    __shared__ unsigned short z1s[64 * Z1LD];
    __shared__ float redA[512];
    __shared__ float redB[512];
    const int tid = threadIdx.x;
    const int w = tid >> 6, lane = tid & 63;
    const int q = lane >> 4, l15 = lane & 15;
    const int row0 = blockIdx.x * 64 + w * 16;

    const int ar = min(row0 + l15, N_NODES - 1);
    const unsigned short* aptr = zb + (size_t)ar * HID + q * 8;

    f32x4 acc[8];
#pragma unroll
    for (int nt = 0; nt < 8; ++nt) acc[nt] = (f32x4){0.f, 0.f, 0.f, 0.f};

#pragma unroll
    for (int ks = 0; ks < 4; ++ks) {
        const short8 a = *(const short8*)(aptr + ks * 32);
#pragma unroll
        for (int nt = 0; nt < 8; ++nt) {
            const short8 b = *(const short8*)(w1p + (((ks << 3) + nt) * 64 + lane) * 8);
            acc[nt] = __builtin_amdgcn_mfma_f32_16x16x32_bf16(a, b, acc[nt], 0, 0, 0);
        }
    }
    {
        const int lr0 = w * 16 + q * 4;
#pragma unroll
        for (int nt = 0; nt < 8; ++nt) {
            const float bias = b1[nt * 16 + l15];
            const int cc = nt * 16 + l15;
#pragma unroll
            for (int reg = 0; reg < 4; ++reg) {
                const float v = fmaxf(acc[nt][reg] + bias, 0.f);
                z1s[(lr0 + reg) * Z1LD + cc] = (unsigned short)f2bf(v);
            }
        }
    }
#pragma unroll
    for (int nt = 0; nt < 8; ++nt) acc[nt] = (f32x4){0.f, 0.f, 0.f, 0.f};
    const unsigned short* a2p = &z1s[(w * 16 + l15) * Z1LD + q * 8];
#pragma unroll
    for (int ks = 0; ks < 4; ++ks) {
        const short8 a = *(const short8*)(a2p + ks * 32);
#pragma unroll
        for (int nt = 0; nt < 8; ++nt) {
            const short8 b = *(const short8*)(w2p + (((ks << 3) + nt) * 64 + lane) * 8);
            acc[nt] = __builtin_amdgcn_mfma_f32_16x16x32_bf16(a, b, acc[nt], 0, 0, 0);
        }
    }
    float s[8], sq[8];
    const int rowb = row0 + q * 4;
#pragma unroll
    for (int nt = 0; nt < 8; ++nt) {
        const float bias = b2[nt * 16 + l15];
        const int cc = nt * 16 + l15;
        float ls = 0.f, lq = 0.f;
#pragma unroll
        for (int reg = 0; reg < 4; ++reg) {
            const int r = rowb + reg;
            const float v = acc[nt][reg] + bias;
            if (r < N_NODES) {
                z2b[(size_t)r * HID + cc] = (unsigned short)f2bf(v);
                ls += v;
                lq = fmaf(v, v, lq);
            }
        }
        s[nt] = ls; sq[nt] = lq;
    }
#pragma unroll
    for (int nt = 0; nt < 8; ++nt) {
        s[nt] += __shfl_xor(s[nt], 16, 64);
        s[nt] += __shfl_xor(s[nt], 32, 64);
        sq[nt] += __shfl_xor(sq[nt], 16, 64);
        sq[nt] += __shfl_xor(sq[nt], 32, 64);
    }
    if (lane < 16) {
#pragma unroll
        for (int nt = 0; nt < 8; ++nt) {
            redA[w * 128 + nt * 16 + lane] = s[nt];
            redB[w * 128 + nt * 16 + lane] = sq[nt];
        }
    }
    __syncthreads();
    if (tid < 128) {
        float t = redA[tid] + redA[128 + tid] + redA[256 + tid] + redA[384 + tid];
        atomicAdd(&bn[tid], t);
    } else {
        const int c = tid - 128;
        float t = redB[c] + redB[128 + c] + redB[256 + c] + redB[384 + c];
        atomicAdd(&bn[128 + c], t);
    }
}

// ---------------------------------------------------------------------------
// Global add pool (batch sorted), with fused BN+ReLU of the last layer.
// ---------------------------------------------------------------------------
__global__ void k_pool(const unsigned short* __restrict__ z2b, const int* __restrict__ batch,
                       const float* __restrict__ bnst, const float* __restrict__ gamma,
                       const float* __restrict__ beta, float* __restrict__ g) {
    const int f = threadIdx.x;            // 128 threads
    const float invN = 1.0f / (float)N_NODES;
    const float m = bnst[f] * invN;
    const float var = fmaxf(bnst[128 + f] * invN - m * m, 0.f);
    const float r = rsqrtf(var + BN_EPS);
    const float sc = gamma[f] * r;
    const float sh = fmaf(-m, sc, beta[f]);

    const int n0 = blockIdx.x * 128;
    const int nend = min(n0 + 128, N_NODES);
    float acc = 0.f;
    int cur = batch[n0];
    for (int n = n0; n < nend; ++n) {
        const int bb = batch[n];
        if (bb != cur) {
            atomicAdd(&g[cur * HID + f], acc);
            acc = 0.f;
            cur = bb;
        }
        const float raw = bfl((unsigned int)z2b[n * HID + f]);
        acc += fmaxf(fmaf(raw, sc, sh), 0.f);
    }
    atomicAdd(&g[cur * HID + f], acc);
}

// ---------------------------------------------------------------------------
// Head
// ---------------------------------------------------------------------------
__global__ void k_head1(const float* __restrict__ g, const float* __restrict__ W,
                        const float* __restrict__ b, float* __restrict__ g1) {
    const int idx = blockIdx.x * 256 + threadIdx.x;   // 32*256 = 8192
    const int r = idx >> 7, c = idx & 127;
    float acc = b[c];
    for (int k = 0; k < 128; ++k) acc = fmaf(g[r * HID + k], W[k * HID + c], acc);
    g1[idx] = fmaxf(acc, 0.f);
}

__global__ void k_head2(const float* __restrict__ g1, const float* __restrict__ W,
                        const float* __restrict__ b, float* __restrict__ out) {
    const int idx = threadIdx.x;          // 128
    const int r = idx >> 1, c = idx & 1;
    float acc = b[c];
    for (int k = 0; k < 128; ++k) acc = fmaf(g1[r * HID + k], W[k * 2 + c], acc);
    out[idx] = acc;
}

// ---------------------------------------------------------------------------
// Launch
// ---------------------------------------------------------------------------
extern "C" void kernel_launch(void* const* d_in, const int* in_sizes, int n_in,
                              void* d_out, int out_size, void* d_ws, size_t ws_size,
                              hipStream_t stream) {
    const float* x     = (const float*)d_in[0];
    const int*   ei    = (const int*)d_in[1];
    const float* eattr = (const float*)d_in[2];
    const int*   batch = (const int*)d_in[3];
    const float* encW  = (const float*)d_in[4];
    const float* encb  = (const float*)d_in[5];
    const float* eW    = (const float*)d_in[6];
    const float* eb    = (const float*)d_in[7];
    const float* W1    = (const float*)d_in[8];
    const float* b1    = (const float*)d_in[9];
    const float* W2    = (const float*)d_in[10];
    const float* b2    = (const float*)d_in[11];
    const float* gam   = (const float*)d_in[12];
    const float* bet   = (const float*)d_in[13];
    const float* hW1   = (const float*)d_in[14];
    const float* hb1   = (const float*)d_in[15];
    const float* hW2   = (const float*)d_in[16];
    const float* hb2w  = (const float*)d_in[17];
    float* out = (float*)d_out;

    // workspace layout (float-sized slots)
    float* ws = (float*)d_ws;
    unsigned short* z2b = (unsigned short*)ws;              // [0, 3.2M) 6.4M u16
    float* bn  = ws + 3200000;              // 256
    float* g   = ws + 3200256;              // 8,192
    float* g1  = ws + 3208448;              // 8,192
    unsigned short* hb  = (unsigned short*)(ws + 3216640);  // 6.4M u16 (encoder out)
    unsigned int* zb32  = (unsigned int*)(ws + 6416640);    // 3.2M u32
    unsigned short* hb2 = (unsigned short*)(ws + 9616640);  // 6.4M u16 (BN-applied h')
    unsigned short* wekf = (unsigned short*)(ws + 12816640);// 12,288 u16
    unsigned short* wp  = (unsigned short*)(ws + 12822784); // 98,304 u16
    unsigned short* wpe = (unsigned short*)(ws + 12871936); // 8,192 u16
    int* row_ptr = (int*)(ws + 12876032);   // 50,001
    int* cursor  = row_ptr + N_NODES + 1;   // 50,000
    int* elist   = cursor + N_NODES;        // 640,000 (unused, slot kept)
    int* bsums   = elist + N_EDGES;         // 256
    int* src_s   = bsums + 256;             // 640,000 (ends 14,256,289)
    uint4* eattr_h = (uint4*)(ws + 14256292);               // 5.12M floats, 16B aligned

    const int* esrc = ei;
    const int* edst = ei + N_EDGES;

    // CSR build + fused edge materialization (per call)
    hipMemsetAsync(row_ptr, 0, (N_NODES + 1) * sizeof(int), stream);
    k_hist<<<N_EDGES / 256, 256, 0, stream>>>(edst, row_ptr);
    k_blockred<<<196, 256, 0, stream>>>(row_ptr, bsums);
    k_scan_bsums<<<1, 256, 0, stream>>>(bsums, 196);
    k_scan_blocks<<<196, 256, 0, stream>>>(row_ptr, bsums, cursor);
    k_fill<<<N_EDGES / 256, 256, 0, stream>>>(esrc, edst, eattr, cursor, src_s, eattr_h);

    // merged weight packing (edge bias folded into wekf k==16 row)
    k_pack<<<64, 256, 0, stream>>>(W1, W2, encW, eW, eb, wp, wpe, wekf);

    // encoder -> bf16 h (MFMA, reads fp32 x directly)
    k_encm<<<782, 256, 0, stream>>>(x, wpe, encb, hb);

    for (int l = 0; l < N_LAYERS; ++l) {
        const unsigned short* hrow;
        if (l == 0) {
            hrow = hb;
        } else {
            // materialize h' = relu(BN(z_prev)) once per node
            k_bn<<<3125, 256, 0, stream>>>(z2b, bn, gam + (l - 1) * HID,
                                           bet + (l - 1) * HID, hb2);
            hrow = hb2;
        }
        k_agg<<<1024, 256, 0, stream>>>(hrow, src_s, eattr_h,
                                        wekf + (size_t)l * 4096, row_ptr, zb32);
        hipMemsetAsync(bn, 0, 256 * sizeof(float), stream);
        k_mlp<<<782, 256, 0, stream>>>((const unsigned short*)zb32,
                                       wp + (size_t)l * 16384, b1 + l * HID,
                                       wp + (size_t)(3 + l) * 16384, b2 + l * HID,
                                       z2b, bn);
    }

    hipMemsetAsync(g, 0, NUM_GRAPHS * HID * sizeof(float), stream);
    k_pool<<<391, 128, 0, stream>>>(z2b, batch, bn, gam + 2 * HID, bet + 2 * HID, g);
    k_head1<<<32, 256, 0, stream>>>(g, hW1, hb1, g1);
    k_head2<<<1, 128, 0, stream>>>(g1, hW2, hb2w, out);
}